// Round 1
// baseline (101.438 us; speedup 1.0000x reference)
//
#include <hip/hip_runtime.h>

// Problem constants (fixed by reference): S=256, B=64, D=1024, T=64
#define SLEN 256
#define NB   64
#define ND   1024
#define NT   64
// BOS=0, EOS=1, PAD=2

typedef float f32x4  __attribute__((ext_vector_type(4)));
typedef short bf16x8 __attribute__((ext_vector_type(8)));   // 8 bf16 in 4 VGPRs (guide §3)

__device__ __forceinline__ unsigned cvt_pk_bf16(float lo, float hi) {
  unsigned r;
  asm("v_cvt_pk_bf16_f32 %0, %1, %2" : "=v"(r) : "v"(lo), "v"(hi));
  return r;
}

__device__ __forceinline__ bf16x8 pack_bf16x8(f32x4 a, f32x4 b) {
  union { unsigned u[4]; bf16x8 v; } r;
  r.u[0] = cvt_pk_bf16(a.x, a.y);
  r.u[1] = cvt_pk_bf16(a.z, a.w);
  r.u[2] = cvt_pk_bf16(b.x, b.y);
  r.u[3] = cvt_pk_bf16(b.z, b.w);
  return r.v;
}

// ---------------------------------------------------------------------------
// Kernel 0: W[t][k] f32 -> bf16 "frag-stream" layout so GEMM B-fragments are
// single coalesced 16B loads:  Wb3[((k0*4+f)*64 + lane)*8 + e]
//   = bf16( W[ f*16 + (lane&15) ][ k0*32 + (lane>>4)*8 + e ] )
// (B-frag layout for mfma_f32_16x16x32_bf16: col = lane&15, k = (lane>>4)*8+e)
// ---------------------------------------------------------------------------
__global__ __launch_bounds__(256) void prep_w(const float* __restrict__ W,
                                              unsigned short* __restrict__ Wb3) {
  int o  = blockIdx.x * 256 + threadIdx.x;          // 0..65535
  int e  = o & 7;
  int l  = (o >> 3) & 63;
  int f  = (o >> 9) & 3;
  int k0 = o >> 11;
  int t  = f * 16 + (l & 15);
  int k  = k0 * 32 + ((l >> 4) << 3) + e;
  unsigned u = __float_as_uint(W[t * ND + k]);
  Wb3[o] = (unsigned short)((u + 0x7FFFu + ((u >> 16) & 1u)) >> 16);  // RNE
}

// ---------------------------------------------------------------------------
// Kernel 1: emit[r][t] = sum_k features[r][k]*W[t][k] + b[t],  r = s*B+b flat.
// One wave per 16-row strip, 4 MFMA accumulators (t-blocks 0/16/32/48),
// K swept in 32-wide steps, 4 steps per load group for memory-level parallelism.
// ---------------------------------------------------------------------------
__global__ __launch_bounds__(256) void emit_gemm(const float* __restrict__ F,
                                                 const unsigned short* __restrict__ Wb3,
                                                 const float* __restrict__ bias,
                                                 float* __restrict__ emit) {
  const int lane = threadIdx.x & 63;
  const int wv   = (blockIdx.x * 256 + threadIdx.x) >> 6;  // 0..1023
  const int r0   = wv * 16;
  const int m    = lane & 15;      // A row within strip / output col within frag
  const int kg   = lane >> 4;      // k-group 0..3
  const float* arow = F + (size_t)(r0 + m) * ND + kg * 8;
  const bf16x8* bptr = reinterpret_cast<const bf16x8*>(Wb3) + lane;

  f32x4 acc0 = {0.f, 0.f, 0.f, 0.f};
  f32x4 acc1 = acc0, acc2 = acc0, acc3 = acc0;

  for (int g = 0; g < 32; g += 4) {
    f32x4  a[4][2];
    bf16x8 bb[4][4];
#pragma unroll
    for (int q = 0; q < 4; ++q) {
      a[q][0] = *(const f32x4*)(arow + (g + q) * 32);
      a[q][1] = *(const f32x4*)(arow + (g + q) * 32 + 4);
#pragma unroll
      for (int f = 0; f < 4; ++f) bb[q][f] = bptr[((g + q) * 4 + f) * 64];
    }
#pragma unroll
    for (int q = 0; q < 4; ++q) {
      bf16x8 af = pack_bf16x8(a[q][0], a[q][1]);
      acc0 = __builtin_amdgcn_mfma_f32_16x16x32_bf16(af, bb[q][0], acc0, 0, 0, 0);
      acc1 = __builtin_amdgcn_mfma_f32_16x16x32_bf16(af, bb[q][1], acc1, 0, 0, 0);
      acc2 = __builtin_amdgcn_mfma_f32_16x16x32_bf16(af, bb[q][2], acc2, 0, 0, 0);
      acc3 = __builtin_amdgcn_mfma_f32_16x16x32_bf16(af, bb[q][3], acc3, 0, 0, 0);
    }
  }

  // D layout (verified m89/m91): col = lane&15, row = (lane>>4)*4 + reg
  const float bv0 = bias[m], bv1 = bias[16 + m], bv2 = bias[32 + m], bv3 = bias[48 + m];
  float* op = emit + (size_t)(r0 + kg * 4) * NT + m;
#pragma unroll
  for (int r = 0; r < 4; ++r) {
    op[r * NT +  0] = acc0[r] + bv0;
    op[r * NT + 16] = acc1[r] + bv1;
    op[r * NT + 32] = acc2[r] + bv2;
    op[r * NT + 48] = acc3[r] + bv3;
  }
}

// ---------------------------------------------------------------------------
// Kernel 2: per-batch CRF forward recursion (linear space) + gold score.
// Lane j owns tag j. E[i][j]=exp(trans[i][j]) lives in 64 VGPRs of lane j.
// Per step: w_i = A_i * exp(emit[t,b,i]); A'_j = sum_i w_i * E[i][j].
// Exact power-of-2 renorm every 8 steps keeps A in f32 range; logZ tracks it.
// ---------------------------------------------------------------------------
__global__ __launch_bounds__(64) void crf_fwd(const float* __restrict__ emit,
                                              const float* __restrict__ trans,
                                              const int*   __restrict__ tags,
                                              const int*   __restrict__ seq_lens,
                                              float* __restrict__ partials) {
  __shared__ __align__(16) float elds[64];
  const int b = blockIdx.x;
  const int j = threadIdx.x;

  float E[64];
#pragma unroll
  for (int i = 0; i < 64; ++i) E[i] = __expf(trans[i * 64 + j]);

  const int L = seq_lens[b];   // in [2, 256]

  // gold = sum_{s<L} emit[s,b,tag_s] + trans[tag_s, tag_{s+1} (PAD at s=S-1)]
  float gold = 0.f;
  for (int s = j; s < L; s += 64) {
    int tg = tags[s * 64 + b];
    int nx = (s + 1 < SLEN) ? tags[(s + 1) * 64 + b] : 2;
    gold += emit[(size_t)(s * 64 + b) * 64 + tg] + trans[tg * 64 + nx];
  }
#pragma unroll
  for (int off = 32; off; off >>= 1) gold += __shfl_xor(gold, off, 64);

  // t=0: alpha_j = emit[0,b,BOS] + trans[BOS][j]
  float a0 = emit[(size_t)b * 64 + 0] + trans[j];
  float m0 = __uint_as_float(__builtin_amdgcn_readfirstlane(__float_as_uint(a0)));
  float A    = __expf(a0 - m0);
  float logZ = m0;

  const float* erow = emit + (size_t)b * 64 + j;   // + t*4096 per step

#define CRF_STEP(U) {                                                    \
    const int t_ = g + (U);                                              \
    if (t_ >= 1 && t_ < L) {                                             \
      elds[j] = A * xv[U];          /* same-wave DS ops are in order */  \
      float s0 = 0.f, s1 = 0.f, s2 = 0.f, s3 = 0.f;                      \
      _Pragma("unroll")                                                  \
      for (int i = 0; i < 64; i += 4) {                                  \
        f32x4 ev = *(const f32x4*)(elds + i);   /* uniform: broadcast */ \
        s0 = fmaf(ev.x, E[i + 0], s0);                                   \
        s1 = fmaf(ev.y, E[i + 1], s1);                                   \
        s2 = fmaf(ev.z, E[i + 2], s2);                                   \
        s3 = fmaf(ev.w, E[i + 3], s3);                                   \
      }                                                                  \
      A = (s0 + s1) + (s2 + s3);                                         \
    } }

#define CRF_RENORM {                                                     \
    unsigned bb_ = __builtin_amdgcn_readfirstlane(__float_as_uint(A));   \
    int ex_ = (int)((bb_ >> 23) & 0xFFu) - 127;                          \
    A *= __uint_as_float((unsigned)(127 - ex_) << 23);                   \
    logZ += (float)ex_ * 0.693147180559945f; }

  for (int g = 0; g < SLEN; g += 16) {
    float xv[16];
#pragma unroll
    for (int u = 0; u < 16; ++u) xv[u] = erow[(size_t)(g + u) * (NB * NT)];
#pragma unroll
    for (int u = 0; u < 16; ++u) xv[u] = __expf(xv[u]);

    CRF_STEP(0)  CRF_STEP(1)  CRF_STEP(2)  CRF_STEP(3)
    CRF_STEP(4)  CRF_STEP(5)  CRF_STEP(6)  CRF_STEP(7)
    CRF_RENORM
    CRF_STEP(8)  CRF_STEP(9)  CRF_STEP(10) CRF_STEP(11)
    CRF_STEP(12) CRF_STEP(13) CRF_STEP(14) CRF_STEP(15)
    CRF_RENORM

    if (g + 16 >= L) break;   // steps run only while t < L (uniform per block)
  }
#undef CRF_STEP
#undef CRF_RENORM

  float alphaE = logZ + __logf(A);
  alphaE = __shfl(alphaE, 1, 64);           // EOS = 1
  if (j == 0) partials[b] = alphaE - gold;
}

// ---------------------------------------------------------------------------
// Kernel 3: out[0] = sum_b partials[b]
// ---------------------------------------------------------------------------
__global__ __launch_bounds__(64) void final_reduce(const float* __restrict__ partials,
                                                   float* __restrict__ out) {
  float v = partials[threadIdx.x];
#pragma unroll
  for (int off = 32; off; off >>= 1) v += __shfl_xor(v, off, 64);
  if (threadIdx.x == 0) out[0] = v;
}

extern "C" void kernel_launch(void* const* d_in, const int* in_sizes, int n_in,
                              void* d_out, int out_size, void* d_ws, size_t ws_size,
                              hipStream_t stream) {
  const float* F     = (const float*)d_in[0];   // features (S,B,D) f32
  const int*   tags  = (const int*)  d_in[1];   // (S,B) i32
  const int*   seq   = (const int*)  d_in[2];   // (B,) i32
  const float* W     = (const float*)d_in[3];   // (T,D) f32
  const float* bias  = (const float*)d_in[4];   // (T,) f32
  const float* trans = (const float*)d_in[5];   // (T,T) f32
  float* out = (float*)d_out;

  char* ws = (char*)d_ws;
  float*          emit     = (float*)ws;                                   // 4 MiB
  unsigned short* Wb3      = (unsigned short*)(ws + (size_t)4 * 1024 * 1024); // 128 KiB
  float*          partials = (float*)(ws + (size_t)4 * 1024 * 1024 + 131072); // 256 B

  prep_w   <<<256, 256, 0, stream>>>(W, Wb3);
  emit_gemm<<<256, 256, 0, stream>>>(F, Wb3, bias, emit);
  crf_fwd  <<<64,   64, 0, stream>>>(emit, trans, tags, seq, partials);
  final_reduce<<<1, 64, 0, stream>>>(partials, out);
}